// Round 8
// baseline (474.910 us; speedup 1.0000x reference)
//
#include <hip/hip_runtime.h>
#include <cfloat>

#define N_NODES 50000
#define E0      800000
#define EP      850000   // E0 + N_NODES self-loops
#define NGRAPH  512
#define HID     128
#define NEG_SLOPE 0.2f
#define GTILE   32       // gemm node-tile
#define SCHUNK  49       // scan: ceil(50000/1024) elements per thread

// ---------------- CSR build ----------------
__global__ __launch_bounds__(256) void k_hist(const int* __restrict__ dst0, int* __restrict__ cnt){
  int e = blockIdx.x*256 + threadIdx.x;
  if (e < E0) atomicAdd(&cnt[dst0[e]], 1);
}

// single-block scan over all 50000 counts (replaces scan1/scan2/scan3)
__global__ __launch_bounds__(1024) void k_scan_all(const int* __restrict__ cnt,
    int* __restrict__ row_start, int* __restrict__ fill){
  __shared__ int sbuf[1024];
  int tid = threadIdx.x;
  int base = tid*SCHUNK;
  int s = 0;
  for (int i=0;i<SCHUNK;++i){ int idx=base+i; if (idx<N_NODES) s += cnt[idx]+1; } // +1 self-loop
  sbuf[tid] = s; __syncthreads();
  for (int off=1; off<1024; off<<=1){
    int add = (tid>=off)? sbuf[tid-off] : 0;
    __syncthreads();
    sbuf[tid] += add;
    __syncthreads();
  }
  int run = sbuf[tid] - s;               // exclusive prefix
  for (int i=0;i<SCHUNK;++i){
    int idx=base+i;
    if (idx<N_NODES){ row_start[idx]=run; fill[idx]=run; run += cnt[idx]+1; }
  }
  if (tid==1023) row_start[N_NODES] = sbuf[1023];   // == EP
}

__global__ __launch_bounds__(256) void k_scatter(const int* __restrict__ src0, const int* __restrict__ dst0,
    int* __restrict__ fill, int* __restrict__ col_src){
  int i = blockIdx.x*256 + threadIdx.x;
  if (i >= EP) return;
  int s, d;
  if (i < E0){ s = src0[i]; d = dst0[i]; }
  else       { s = i - E0;  d = s; }          // self-loop
  int slot = atomicAdd(&fill[d], 1);
  col_src[slot] = s;
}

// ---------------- dual GEMM: xl = x@Wl, xr = x@Wr ----------------
// Software-pipelined: W chunks double-buffered in registers (A/B, static
// indexing), launch_bounds(128,2) to allow ~200 VGPR so the compiler keeps
// acc(64)+W(64)+x(32) live and overlaps L2 loads with FMAs.
#define GEMM_CHUNK(KB, WLB, WRB)                                            \
  {                                                                         \
    float4 a4[8];                                                           \
    _Pragma("unroll")                                                       \
    for (int i2=0;i2<8;++i2) a4[i2] = *(const float4*)&xs[ngrp*8+i2][KB];   \
    _Pragma("unroll")                                                       \
    for (int i2=0;i2<8;++i2){                                               \
      const float* av = (const float*)&a4[i2];                              \
      _Pragma("unroll")                                                     \
      for (int kk2=0;kk2<4;++kk2){                                          \
        float a = av[kk2];                                                  \
        const float* pl = (const float*)&WLB[kk2];                          \
        const float* pr = (const float*)&WRB[kk2];                          \
        _Pragma("unroll")                                                   \
        for (int j2=0;j2<4;++j2){                                           \
          accl[i2][j2] = fmaf(a, pl[j2], accl[i2][j2]);                     \
          accr[i2][j2] = fmaf(a, pr[j2], accr[i2][j2]);                     \
        }                                                                   \
      }                                                                     \
    }                                                                       \
  }

__global__ __launch_bounds__(128, 2) void k_gemm(const float* __restrict__ x,
    const float* __restrict__ Wl, const float* __restrict__ Wr,
    float* __restrict__ xl, float* __restrict__ xr){
  __shared__ float xs[GTILE][128];   // 16 KB
  int tid = threadIdx.x;
  int n0 = blockIdx.x * GTILE;
  #pragma unroll
  for (int it=0; it<8; ++it){
    int f = it*512 + tid*4;
    int r = f >> 7, c = f & 127;
    float4 v = make_float4(0.f,0.f,0.f,0.f);
    if (n0 + r < N_NODES) v = *(const float4*)&x[(size_t)(n0+r)*128 + c];
    *(float4*)&xs[r][c] = v;
  }
  __syncthreads();
  int cgrp = tid & 31, ngrp = tid >> 5;
  int c4 = cgrp*4;
  const float* Wlp = Wl + c4;
  const float* Wrp = Wr + c4;
  float accl[8][4], accr[8][4];
  #pragma unroll
  for (int i=0;i<8;++i)
    #pragma unroll
    for (int j=0;j<4;++j){ accl[i][j]=0.f; accr[i][j]=0.f; }

  float4 wlA[4], wrA[4], wlB[4], wrB[4];
  #pragma unroll
  for (int kk=0;kk<4;++kk){
    wlA[kk] = *(const float4*)&Wlp[(size_t)kk*128];
    wrA[kk] = *(const float4*)&Wrp[(size_t)kk*128];
  }
  for (int k=0; k<128; k+=8){
    #pragma unroll
    for (int kk=0;kk<4;++kk){                       // prefetch k+4 into B
      wlB[kk] = *(const float4*)&Wlp[(size_t)(k+4+kk)*128];
      wrB[kk] = *(const float4*)&Wrp[(size_t)(k+4+kk)*128];
    }
    GEMM_CHUNK(k, wlA, wrA)                          // compute k with A
    if (k+8 < 128){
      #pragma unroll
      for (int kk=0;kk<4;++kk){                     // prefetch k+8 into A
        wlA[kk] = *(const float4*)&Wlp[(size_t)(k+8+kk)*128];
        wrA[kk] = *(const float4*)&Wrp[(size_t)(k+8+kk)*128];
      }
    }
    GEMM_CHUNK(k+4, wlB, wrB)                        // compute k+4 with B
  }
  #pragma unroll
  for (int i=0;i<8;++i){
    int node = n0 + ngrp*8 + i;
    if (node < N_NODES){
      float4 vl = make_float4(accl[i][0], accl[i][1], accl[i][2], accl[i][3]);
      float4 vr = make_float4(accr[i][0], accr[i][1], accr[i][2], accr[i][3]);
      *(float4*)&xl[(size_t)node*128 + c4] = vl;
      *(float4*)&xr[(size_t)node*128 + c4] = vr;
    }
  }
}

// ---------------- fused GATv2 attention, one wave per dst node ----------------
// 16-lane head reduction via DPP butterfly (VALU-only, no DS ops):
// xor1 (quad_perm[1,0,3,2]=0xB1), xor2 (quad_perm[2,3,0,1]=0x4E),
// xor7 (row_half_mirror=0x141), xor15 (row_mirror=0x140) — sums all 16 lanes.
#define DPP_ADD(x, ctrl) ((x) + __int_as_float(__builtin_amdgcn_update_dpp( \
    0, __float_as_int(x), (ctrl), 0xf, 0xf, true)))
__device__ __forceinline__ float red16(float t){
  t = DPP_ADD(t, 0xB1);
  t = DPP_ADD(t, 0x4E);
  t = DPP_ADD(t, 0x141);
  t = DPP_ADD(t, 0x140);
  return t;
}

__device__ __forceinline__ float lrdot(float2 v, float2 xr2, float2 at2){
  float ex = v.x + xr2.x, ey = v.y + xr2.y;
  ex = ex > 0.f ? ex : NEG_SLOPE*ex;
  ey = ey > 0.f ? ey : NEG_SLOPE*ey;
  return ex*at2.x + ey*at2.y;
}

__global__ __launch_bounds__(256) void k_attn(
    const float* __restrict__ xl, const float* __restrict__ xr,
    const int* __restrict__ row_start, const int* __restrict__ col_src,
    const float* __restrict__ attv, const float* __restrict__ bias,
    const float* __restrict__ Wrel, const float* __restrict__ Wroot,
    const float* __restrict__ brel,
    float* __restrict__ out, float* __restrict__ pbuf, float* __restrict__ score){
  int wid = blockIdx.x*4 + (threadIdx.x >> 6);
  if (wid >= N_NODES) return;
  int lane = threadIdx.x & 63;
  int c2 = lane*2;                       // channels 2l, 2l+1 ; head = lane>>4
  float2 xr2 = *(const float2*)&xr[(size_t)wid*128 + c2];
  float2 at2 = *(const float2*)&attv[c2];
  int row = row_start[wid];
  int deg = row_start[wid+1] - row;
  float d = 0.f, ax = 0.f, ay = 0.f;
  int i = 0;
  for (; i+4 <= deg; i += 4){
    int s0 = col_src[row+i+0];
    int s1 = col_src[row+i+1];
    int s2 = col_src[row+i+2];
    int s3 = col_src[row+i+3];
    float2 v0 = *(const float2*)&xl[(size_t)s0*128 + c2];
    float2 v1 = *(const float2*)&xl[(size_t)s1*128 + c2];
    float2 v2 = *(const float2*)&xl[(size_t)s2*128 + c2];
    float2 v3 = *(const float2*)&xl[(size_t)s3*128 + c2];
    float t0 = red16(lrdot(v0, xr2, at2));
    float t1 = red16(lrdot(v1, xr2, at2));
    float t2 = red16(lrdot(v2, xr2, at2));
    float t3 = red16(lrdot(v3, xr2, at2));
    float w0 = __expf(t0), w1 = __expf(t1), w2 = __expf(t2), w3 = __expf(t3);
    d += (w0 + w1) + (w2 + w3);
    ax = fmaf(w3, v3.x, fmaf(w2, v2.x, fmaf(w1, v1.x, fmaf(w0, v0.x, ax))));
    ay = fmaf(w3, v3.y, fmaf(w2, v2.y, fmaf(w1, v1.y, fmaf(w0, v0.y, ay))));
  }
  for (; i < deg; ++i){
    int s = col_src[row+i];
    float2 v = *(const float2*)&xl[(size_t)s*128 + c2];
    float t = red16(lrdot(v, xr2, at2));
    float w = __expf(t);
    d += w;
    ax = fmaf(w, v.x, ax);
    ay = fmaf(w, v.y, ay);
  }
  float inv = 1.f/d;
  float ox = fmaf(ax, inv, bias[c2]);
  float oy = fmaf(ay, inv, bias[c2+1]);
  *(float2*)&out[(size_t)wid*128 + c2] = make_float2(ox, oy);
  float pv = ox*Wrel[c2]  + oy*Wrel[c2+1];
  float rv = ox*Wroot[c2] + oy*Wroot[c2+1];
  #pragma unroll
  for (int off=1; off<64; off<<=1){
    pv += __shfl_xor(pv, off);
    rv += __shfl_xor(rv, off);
  }
  if (lane == 0){
    pbuf[wid]  = pv;
    score[wid] = brel[0] + rv;         // root+bias part; neighbor part added by k_score_edges
  }
}

// ---------------- SAGPool score: edge-parallel atomic accumulate ----------------
// score[n] (init = b_rel + out.W_root from k_attn) += sum_{e: dst=n} pbuf[src]
// Uses raw E0 edge list (no self-loops in reference's GraphConv agg).
__global__ __launch_bounds__(256) void k_score_edges(
    const int* __restrict__ src0, const int* __restrict__ dst0,
    const float* __restrict__ pbuf, float* __restrict__ score){
  int e = blockIdx.x*256 + threadIdx.x;
  if (e < E0) atomicAdd(&score[dst0[e]], pbuf[src0[e]]);
}

// ---------------- per-graph softmax + weighted add-pool (batch_index sorted) ----------------
__device__ __forceinline__ int lbound(const int* __restrict__ a, int n, int v){
  int lo=0, hi=n;
  while (lo < hi){ int mid=(lo+hi)>>1; if (a[mid] < v) lo = mid+1; else hi = mid; }
  return lo;
}

__global__ __launch_bounds__(128) void k_pool(
    const int* __restrict__ batch, const float* __restrict__ score,
    const float* __restrict__ out, float* __restrict__ g){
  int b = blockIdx.x;
  int tid = threadIdx.x;
  int start = lbound(batch, N_NODES, b);
  int end   = lbound(batch, N_NODES, b+1);
  __shared__ float red[128];
  __shared__ float sl[128];
  float lm = -FLT_MAX;
  for (int i=start+tid; i<end; i+=128) lm = fmaxf(lm, score[i]);
  red[tid]=lm; __syncthreads();
  for (int off=64; off>0; off>>=1){ if (tid<off) red[tid]=fmaxf(red[tid],red[tid+off]); __syncthreads(); }
  float m = red[0]; __syncthreads();
  float ls = 0.f;
  for (int i=start+tid; i<end; i+=128) ls += __expf(score[i]-m);
  red[tid]=ls; __syncthreads();
  for (int off=64; off>0; off>>=1){ if (tid<off) red[tid]+=red[tid+off]; __syncthreads(); }
  float inv = 1.f / fmaxf(red[0], 1e-16f);
  __syncthreads();
  float acc = 0.f;
  for (int base=start; base<end; base+=128){
    int idx = base+tid;
    sl[tid] = (idx<end) ? __expf(score[idx]-m)*inv : 0.f;
    __syncthreads();
    int lim = min(128, end-base);
    for (int jj=0; jj<lim; ++jj) acc = fmaf(out[(size_t)(base+jj)*128 + tid], sl[jj], acc);
    __syncthreads();
  }
  g[b*128 + tid] = acc;
}

// ---------------- launch ----------------
extern "C" void kernel_launch(void* const* d_in, const int* in_sizes, int n_in,
                              void* d_out, int out_size, void* d_ws, size_t ws_size,
                              hipStream_t stream){
  const float* x    = (const float*)d_in[0];
  const int*   ei   = (const int*)d_in[1];
  const int*   batch= (const int*)d_in[2];
  const float* Wl   = (const float*)d_in[3];
  const float* Wr   = (const float*)d_in[4];
  const float* attv = (const float*)d_in[5];
  const float* bias = (const float*)d_in[6];
  const float* Wrel = (const float*)d_in[7];
  const float* brel = (const float*)d_in[8];
  const float* Wroot= (const float*)d_in[9];
  const int* src0 = ei;
  const int* dst0 = ei + E0;

  float* out = (float*)d_out;                    // [N,128]
  float* g   = out + (size_t)N_NODES*HID;        // [512,128]

  float* xl = (float*)d_ws;
  float* xr = xl + (size_t)N_NODES*HID;
  int* cnt       = (int*)(xr + (size_t)N_NODES*HID);
  int* row_start = cnt + N_NODES;                // N+1
  int* fill      = row_start + N_NODES + 1;
  int* col_src   = fill + N_NODES;               // EP
  float* pbuf    = (float*)(col_src + EP);
  float* score   = pbuf + N_NODES;

  hipMemsetAsync(cnt, 0, N_NODES*sizeof(int), stream);
  k_gemm       <<<dim3((N_NODES+GTILE-1)/GTILE), 128, 0, stream>>>(x, Wl, Wr, xl, xr);
  k_hist       <<<dim3((E0+255)/256),   256, 0, stream>>>(dst0, cnt);
  k_scan_all   <<<dim3(1),             1024, 0, stream>>>(cnt, row_start, fill);
  k_scatter    <<<dim3((EP+255)/256),   256, 0, stream>>>(src0, dst0, fill, col_src);
  k_attn       <<<dim3(N_NODES/4),      256, 0, stream>>>(xl, xr, row_start, col_src,
                                                          attv, bias, Wrel, Wroot, brel,
                                                          out, pbuf, score);
  k_score_edges<<<dim3((E0+255)/256),   256, 0, stream>>>(src0, dst0, pbuf, score);
  k_pool       <<<dim3(NGRAPH),         128, 0, stream>>>(batch, score, out, g);
}

// Round 10
// 369.610 us; speedup vs baseline: 1.2849x; 1.2849x over previous
//
#include <hip/hip_runtime.h>
#include <cfloat>

#define N_NODES 50000
#define E0      800000
#define EP      850000   // E0 + N_NODES self-loops
#define NGRAPH  512
#define HID     128
#define NB_SCAN 49       // ceil(50000/1024)
#define NEG_SLOPE 0.2f
#define GTILE   32       // gemm node-tile

// ---------------- CSR build ----------------
__global__ __launch_bounds__(256) void k_hist(const int* __restrict__ dst0, int* __restrict__ cnt){
  int e = blockIdx.x*256 + threadIdx.x;
  if (e < E0) atomicAdd(&cnt[dst0[e]], 1);
}

// 3-phase multi-block scan (proven ≤~15 µs total; single-block fusion was 125 µs)
__global__ __launch_bounds__(256) void k_scan1(const int* __restrict__ cnt, int* __restrict__ bsum){
  __shared__ int red[256];
  int tid = threadIdx.x;
  int base = blockIdx.x*1024 + tid*4;
  int s = 0;
  #pragma unroll
  for (int i=0;i<4;++i){ int idx = base+i; if (idx < N_NODES) s += cnt[idx] + 1; } // +1 self-loop
  red[tid] = s; __syncthreads();
  for (int off=128; off>0; off>>=1){ if (tid<off) red[tid]+=red[tid+off]; __syncthreads(); }
  if (tid==0) bsum[blockIdx.x] = red[0];
}

__global__ void k_scan2(const int* __restrict__ bsum, int* __restrict__ boff, int* __restrict__ row_start){
  if (threadIdx.x == 0){
    int run = 0;
    for (int b=0;b<NB_SCAN;++b){ boff[b] = run; run += bsum[b]; }
    row_start[N_NODES] = run;   // == EP
  }
}

__global__ __launch_bounds__(256) void k_scan3(const int* __restrict__ cnt, const int* __restrict__ boff,
    int* __restrict__ row_start, int* __restrict__ fill){
  __shared__ int sbuf[256];
  int tid = threadIdx.x;
  int base = blockIdx.x*1024 + tid*4;
  int v[4]; int ts = 0;
  #pragma unroll
  for (int i=0;i<4;++i){ int idx=base+i; v[i] = (idx<N_NODES)? cnt[idx]+1 : 0; ts += v[i]; }
  sbuf[tid] = ts; __syncthreads();
  for (int off=1; off<256; off<<=1){
    int add = (tid>=off)? sbuf[tid-off] : 0;
    __syncthreads();
    sbuf[tid] += add;
    __syncthreads();
  }
  int run = boff[blockIdx.x] + sbuf[tid] - ts;   // exclusive prefix for this thread
  #pragma unroll
  for (int i=0;i<4;++i){
    int idx = base+i;
    if (idx < N_NODES){ row_start[idx]=run; fill[idx]=run; run += v[i]; }
  }
}

__global__ __launch_bounds__(256) void k_scatter(const int* __restrict__ src0, const int* __restrict__ dst0,
    int* __restrict__ fill, int* __restrict__ col_src){
  int i = blockIdx.x*256 + threadIdx.x;
  if (i >= EP) return;
  int s, d;
  if (i < E0){ s = src0[i]; d = dst0[i]; }
  else       { s = i - E0;  d = s; }          // self-loop
  int slot = atomicAdd(&fill[d], 1);
  col_src[slot] = s;
}

// ---------------- dual GEMM: xl = x@Wl, xr = x@Wr ----------------
// Software-pipelined: W chunks double-buffered in registers (A/B, static
// indexing), launch_bounds(128,2) to allow ~200 VGPR so the compiler keeps
// acc(64)+W(64)+x(32) live and overlaps L2 loads with FMAs.
#define GEMM_CHUNK(KB, WLB, WRB)                                            \
  {                                                                         \
    float4 a4[8];                                                           \
    _Pragma("unroll")                                                       \
    for (int i2=0;i2<8;++i2) a4[i2] = *(const float4*)&xs[ngrp*8+i2][KB];   \
    _Pragma("unroll")                                                       \
    for (int i2=0;i2<8;++i2){                                               \
      const float* av = (const float*)&a4[i2];                              \
      _Pragma("unroll")                                                     \
      for (int kk2=0;kk2<4;++kk2){                                          \
        float a = av[kk2];                                                  \
        const float* pl = (const float*)&WLB[kk2];                          \
        const float* pr = (const float*)&WRB[kk2];                          \
        _Pragma("unroll")                                                   \
        for (int j2=0;j2<4;++j2){                                           \
          accl[i2][j2] = fmaf(a, pl[j2], accl[i2][j2]);                     \
          accr[i2][j2] = fmaf(a, pr[j2], accr[i2][j2]);                     \
        }                                                                   \
      }                                                                     \
    }                                                                       \
  }

__global__ __launch_bounds__(128, 2) void k_gemm(const float* __restrict__ x,
    const float* __restrict__ Wl, const float* __restrict__ Wr,
    float* __restrict__ xl, float* __restrict__ xr){
  __shared__ float xs[GTILE][128];   // 16 KB
  int tid = threadIdx.x;
  int n0 = blockIdx.x * GTILE;
  #pragma unroll
  for (int it=0; it<8; ++it){
    int f = it*512 + tid*4;
    int r = f >> 7, c = f & 127;
    float4 v = make_float4(0.f,0.f,0.f,0.f);
    if (n0 + r < N_NODES) v = *(const float4*)&x[(size_t)(n0+r)*128 + c];
    *(float4*)&xs[r][c] = v;
  }
  __syncthreads();
  int cgrp = tid & 31, ngrp = tid >> 5;
  int c4 = cgrp*4;
  const float* Wlp = Wl + c4;
  const float* Wrp = Wr + c4;
  float accl[8][4], accr[8][4];
  #pragma unroll
  for (int i=0;i<8;++i)
    #pragma unroll
    for (int j=0;j<4;++j){ accl[i][j]=0.f; accr[i][j]=0.f; }

  float4 wlA[4], wrA[4], wlB[4], wrB[4];
  #pragma unroll
  for (int kk=0;kk<4;++kk){
    wlA[kk] = *(const float4*)&Wlp[(size_t)kk*128];
    wrA[kk] = *(const float4*)&Wrp[(size_t)kk*128];
  }
  for (int k=0; k<128; k+=8){
    #pragma unroll
    for (int kk=0;kk<4;++kk){                       // prefetch k+4 into B
      wlB[kk] = *(const float4*)&Wlp[(size_t)(k+4+kk)*128];
      wrB[kk] = *(const float4*)&Wrp[(size_t)(k+4+kk)*128];
    }
    GEMM_CHUNK(k, wlA, wrA)                          // compute k with A
    if (k+8 < 128){
      #pragma unroll
      for (int kk=0;kk<4;++kk){                     // prefetch k+8 into A
        wlA[kk] = *(const float4*)&Wlp[(size_t)(k+8+kk)*128];
        wrA[kk] = *(const float4*)&Wrp[(size_t)(k+8+kk)*128];
      }
    }
    GEMM_CHUNK(k+4, wlB, wrB)                        // compute k+4 with B
  }
  #pragma unroll
  for (int i=0;i<8;++i){
    int node = n0 + ngrp*8 + i;
    if (node < N_NODES){
      float4 vl = make_float4(accl[i][0], accl[i][1], accl[i][2], accl[i][3]);
      float4 vr = make_float4(accr[i][0], accr[i][1], accr[i][2], accr[i][3]);
      *(float4*)&xl[(size_t)node*128 + c4] = vl;
      *(float4*)&xr[(size_t)node*128 + c4] = vr;
    }
  }
}

// ---------------- fused GATv2 attention, one wave per dst node ----------------
// 16-lane head reduction via DPP butterfly (VALU-only, no DS ops):
// xor1 (quad_perm[1,0,3,2]=0xB1), xor2 (quad_perm[2,3,0,1]=0x4E),
// xor7 (row_half_mirror=0x141), xor15 (row_mirror=0x140) — sums all 16 lanes.
#define DPP_ADD(x, ctrl) ((x) + __int_as_float(__builtin_amdgcn_update_dpp( \
    0, __float_as_int(x), (ctrl), 0xf, 0xf, true)))
__device__ __forceinline__ float red16(float t){
  t = DPP_ADD(t, 0xB1);
  t = DPP_ADD(t, 0x4E);
  t = DPP_ADD(t, 0x141);
  t = DPP_ADD(t, 0x140);
  return t;
}

__device__ __forceinline__ float lrdot(float2 v, float2 xr2, float2 at2){
  float ex = v.x + xr2.x, ey = v.y + xr2.y;
  ex = ex > 0.f ? ex : NEG_SLOPE*ex;
  ey = ey > 0.f ? ey : NEG_SLOPE*ey;
  return ex*at2.x + ey*at2.y;
}

__global__ __launch_bounds__(256) void k_attn(
    const float* __restrict__ xl, const float* __restrict__ xr,
    const int* __restrict__ row_start, const int* __restrict__ col_src,
    const float* __restrict__ attv, const float* __restrict__ bias,
    const float* __restrict__ Wrel, const float* __restrict__ Wroot,
    const float* __restrict__ brel,
    float* __restrict__ out, float* __restrict__ pbuf, float* __restrict__ score){
  int wid = blockIdx.x*4 + (threadIdx.x >> 6);
  if (wid >= N_NODES) return;
  int lane = threadIdx.x & 63;
  int c2 = lane*2;                       // channels 2l, 2l+1 ; head = lane>>4
  float2 xr2 = *(const float2*)&xr[(size_t)wid*128 + c2];
  float2 at2 = *(const float2*)&attv[c2];
  int row = row_start[wid];
  int deg = row_start[wid+1] - row;
  float d = 0.f, ax = 0.f, ay = 0.f;
  int i = 0;
  for (; i+4 <= deg; i += 4){
    int s0 = col_src[row+i+0];
    int s1 = col_src[row+i+1];
    int s2 = col_src[row+i+2];
    int s3 = col_src[row+i+3];
    float2 v0 = *(const float2*)&xl[(size_t)s0*128 + c2];
    float2 v1 = *(const float2*)&xl[(size_t)s1*128 + c2];
    float2 v2 = *(const float2*)&xl[(size_t)s2*128 + c2];
    float2 v3 = *(const float2*)&xl[(size_t)s3*128 + c2];
    float t0 = red16(lrdot(v0, xr2, at2));
    float t1 = red16(lrdot(v1, xr2, at2));
    float t2 = red16(lrdot(v2, xr2, at2));
    float t3 = red16(lrdot(v3, xr2, at2));
    float w0 = __expf(t0), w1 = __expf(t1), w2 = __expf(t2), w3 = __expf(t3);
    d += (w0 + w1) + (w2 + w3);
    ax = fmaf(w3, v3.x, fmaf(w2, v2.x, fmaf(w1, v1.x, fmaf(w0, v0.x, ax))));
    ay = fmaf(w3, v3.y, fmaf(w2, v2.y, fmaf(w1, v1.y, fmaf(w0, v0.y, ay))));
  }
  for (; i < deg; ++i){
    int s = col_src[row+i];
    float2 v = *(const float2*)&xl[(size_t)s*128 + c2];
    float t = red16(lrdot(v, xr2, at2));
    float w = __expf(t);
    d += w;
    ax = fmaf(w, v.x, ax);
    ay = fmaf(w, v.y, ay);
  }
  float inv = 1.f/d;
  float ox = fmaf(ax, inv, bias[c2]);
  float oy = fmaf(ay, inv, bias[c2+1]);
  *(float2*)&out[(size_t)wid*128 + c2] = make_float2(ox, oy);
  float pv = ox*Wrel[c2]  + oy*Wrel[c2+1];
  float rv = ox*Wroot[c2] + oy*Wroot[c2+1];
  #pragma unroll
  for (int off=1; off<64; off<<=1){
    pv += __shfl_xor(pv, off);
    rv += __shfl_xor(rv, off);
  }
  if (lane == 0){
    pbuf[wid]  = pv;
    score[wid] = brel[0] + rv;         // root+bias part; neighbor part added by k_score_edges
  }
}

// ---------------- SAGPool score: edge-parallel atomic accumulate ----------------
__global__ __launch_bounds__(256) void k_score_edges(
    const int* __restrict__ src0, const int* __restrict__ dst0,
    const float* __restrict__ pbuf, float* __restrict__ score){
  int e = blockIdx.x*256 + threadIdx.x;
  if (e < E0) atomicAdd(&score[dst0[e]], pbuf[src0[e]]);
}

// ---------------- per-graph softmax + weighted add-pool (batch_index sorted) ----------------
__device__ __forceinline__ int lbound(const int* __restrict__ a, int n, int v){
  int lo=0, hi=n;
  while (lo < hi){ int mid=(lo+hi)>>1; if (a[mid] < v) lo = mid+1; else hi = mid; }
  return lo;
}

__global__ __launch_bounds__(128) void k_pool(
    const int* __restrict__ batch, const float* __restrict__ score,
    const float* __restrict__ out, float* __restrict__ g){
  int b = blockIdx.x;
  int tid = threadIdx.x;
  int start = lbound(batch, N_NODES, b);
  int end   = lbound(batch, N_NODES, b+1);
  __shared__ float red[128];
  __shared__ float sl[128];
  float lm = -FLT_MAX;
  for (int i=start+tid; i<end; i+=128) lm = fmaxf(lm, score[i]);
  red[tid]=lm; __syncthreads();
  for (int off=64; off>0; off>>=1){ if (tid<off) red[tid]=fmaxf(red[tid],red[tid+off]); __syncthreads(); }
  float m = red[0]; __syncthreads();
  float ls = 0.f;
  for (int i=start+tid; i<end; i+=128) ls += __expf(score[i]-m);
  red[tid]=ls; __syncthreads();
  for (int off=64; off>0; off>>=1){ if (tid<off) red[tid]+=red[tid+off]; __syncthreads(); }
  float inv = 1.f / fmaxf(red[0], 1e-16f);
  __syncthreads();
  float acc = 0.f;
  for (int base=start; base<end; base+=128){
    int idx = base+tid;
    sl[tid] = (idx<end) ? __expf(score[idx]-m)*inv : 0.f;
    __syncthreads();
    int lim = min(128, end-base);
    for (int jj=0; jj<lim; ++jj) acc = fmaf(out[(size_t)(base+jj)*128 + tid], sl[jj], acc);
    __syncthreads();
  }
  g[b*128 + tid] = acc;
}

// ---------------- launch ----------------
extern "C" void kernel_launch(void* const* d_in, const int* in_sizes, int n_in,
                              void* d_out, int out_size, void* d_ws, size_t ws_size,
                              hipStream_t stream){
  const float* x    = (const float*)d_in[0];
  const int*   ei   = (const int*)d_in[1];
  const int*   batch= (const int*)d_in[2];
  const float* Wl   = (const float*)d_in[3];
  const float* Wr   = (const float*)d_in[4];
  const float* attv = (const float*)d_in[5];
  const float* bias = (const float*)d_in[6];
  const float* Wrel = (const float*)d_in[7];
  const float* brel = (const float*)d_in[8];
  const float* Wroot= (const float*)d_in[9];
  const int* src0 = ei;
  const int* dst0 = ei + E0;

  float* out = (float*)d_out;                    // [N,128]
  float* g   = out + (size_t)N_NODES*HID;        // [512,128]

  float* xl = (float*)d_ws;
  float* xr = xl + (size_t)N_NODES*HID;
  int* cnt       = (int*)(xr + (size_t)N_NODES*HID);
  int* row_start = cnt + N_NODES;                // N+1
  int* fill      = row_start + N_NODES + 1;
  int* bsum      = fill + N_NODES;
  int* boff      = bsum + NB_SCAN;
  int* col_src   = boff + NB_SCAN;               // EP
  float* pbuf    = (float*)(col_src + EP);
  float* score   = pbuf + N_NODES;

  hipMemsetAsync(cnt, 0, N_NODES*sizeof(int), stream);
  k_gemm       <<<dim3((N_NODES+GTILE-1)/GTILE), 128, 0, stream>>>(x, Wl, Wr, xl, xr);
  k_hist       <<<dim3((E0+255)/256),   256, 0, stream>>>(dst0, cnt);
  k_scan1      <<<dim3(NB_SCAN),        256, 0, stream>>>(cnt, bsum);
  k_scan2      <<<dim3(1),               64, 0, stream>>>(bsum, boff, row_start);
  k_scan3      <<<dim3(NB_SCAN),        256, 0, stream>>>(cnt, boff, row_start, fill);
  k_scatter    <<<dim3((EP+255)/256),   256, 0, stream>>>(src0, dst0, fill, col_src);
  k_attn       <<<dim3(N_NODES/4),      256, 0, stream>>>(xl, xr, row_start, col_src,
                                                          attv, bias, Wrel, Wroot, brel,
                                                          out, pbuf, score);
  k_score_edges<<<dim3((E0+255)/256),   256, 0, stream>>>(src0, dst0, pbuf, score);
  k_pool       <<<dim3(NGRAPH),         128, 0, stream>>>(batch, score, out, g);
}

// Round 13
// 326.201 us; speedup vs baseline: 1.4559x; 1.1331x over previous
//
#include <hip/hip_runtime.h>
#include <cfloat>

#define N_NODES 50000
#define E0      800000
#define EP      850000   // E0 + N_NODES self-loops
#define NGRAPH  512
#define HID     128
#define NB_SCAN 49       // ceil(50000/1024)
#define NEG_SLOPE 0.2f
#define GTILE   32       // gemm node-tile

// ---------------- CSR build ----------------
__global__ __launch_bounds__(256) void k_hist(const int* __restrict__ dst0, int* __restrict__ cnt){
  int e = blockIdx.x*256 + threadIdx.x;
  if (e < E0) atomicAdd(&cnt[dst0[e]], 1);
}

__global__ __launch_bounds__(256) void k_scan1(const int* __restrict__ cnt, int* __restrict__ bsum){
  __shared__ int red[256];
  int tid = threadIdx.x;
  int base = blockIdx.x*1024 + tid*4;
  int s = 0;
  #pragma unroll
  for (int i=0;i<4;++i){ int idx = base+i; if (idx < N_NODES) s += cnt[idx] + 1; } // +1 self-loop
  red[tid] = s; __syncthreads();
  for (int off=128; off>0; off>>=1){ if (tid<off) red[tid]+=red[tid+off]; __syncthreads(); }
  if (tid==0) bsum[blockIdx.x] = red[0];
}

// scan3 derives its block offset from bsum via a 64-lane wave reduce
// (49 L2-hot entries; blockIdx.x <= 48 < 64) — k_scan2 launch eliminated.
__global__ __launch_bounds__(256) void k_scan3(const int* __restrict__ cnt, const int* __restrict__ bsum,
    int* __restrict__ row_start, int* __restrict__ fill){
  __shared__ int sbuf[256];
  int tid = threadIdx.x;
  int lane = tid & 63;
  int bv = (lane < blockIdx.x) ? bsum[lane] : 0;      // exclusive: blocks 0..bid-1
  #pragma unroll
  for (int off=32; off>0; off>>=1) bv += __shfl_xor(bv, off);
  int boff = bv;                                       // uniform across wave
  int base = blockIdx.x*1024 + tid*4;
  int v[4]; int ts = 0;
  #pragma unroll
  for (int i=0;i<4;++i){ int idx=base+i; v[i] = (idx<N_NODES)? cnt[idx]+1 : 0; ts += v[i]; }
  sbuf[tid] = ts; __syncthreads();
  for (int off=1; off<256; off<<=1){
    int add = (tid>=off)? sbuf[tid-off] : 0;
    __syncthreads();
    sbuf[tid] += add;
    __syncthreads();
  }
  int run = boff + sbuf[tid] - ts;   // exclusive prefix for this thread
  #pragma unroll
  for (int i=0;i<4;++i){
    int idx = base+i;
    if (idx < N_NODES){ row_start[idx]=run; fill[idx]=run; run += v[i]; }
  }
  if (blockIdx.x == NB_SCAN-1 && tid == 255) row_start[N_NODES] = run;  // == EP
}

__global__ __launch_bounds__(256) void k_scatter(const int* __restrict__ src0, const int* __restrict__ dst0,
    int* __restrict__ fill, int* __restrict__ col_src){
  int i = blockIdx.x*256 + threadIdx.x;
  if (i >= EP) return;
  int s, d;
  if (i < E0){ s = src0[i]; d = dst0[i]; }
  else       { s = i - E0;  d = s; }          // self-loop
  int slot = atomicAdd(&fill[d], 1);
  col_src[slot] = s;
}

// ---------------- dual GEMM: xl = x@Wl, xr = x@Wr ----------------
// Software-pipelined: W chunks double-buffered in registers (A/B, static
// indexing), launch_bounds(128,2) to allow ~200 VGPR so the compiler keeps
// acc(64)+W(64)+x(32) live and overlaps L2 loads with FMAs.
#define GEMM_CHUNK(KB, WLB, WRB)                                            \
  {                                                                         \
    float4 a4[8];                                                           \
    _Pragma("unroll")                                                       \
    for (int i2=0;i2<8;++i2) a4[i2] = *(const float4*)&xs[ngrp*8+i2][KB];   \
    _Pragma("unroll")                                                       \
    for (int i2=0;i2<8;++i2){                                               \
      const float* av = (const float*)&a4[i2];                              \
      _Pragma("unroll")                                                     \
      for (int kk2=0;kk2<4;++kk2){                                          \
        float a = av[kk2];                                                  \
        const float* pl = (const float*)&WLB[kk2];                          \
        const float* pr = (const float*)&WRB[kk2];                          \
        _Pragma("unroll")                                                   \
        for (int j2=0;j2<4;++j2){                                           \
          accl[i2][j2] = fmaf(a, pl[j2], accl[i2][j2]);                     \
          accr[i2][j2] = fmaf(a, pr[j2], accr[i2][j2]);                     \
        }                                                                   \
      }                                                                     \
    }                                                                       \
  }

__global__ __launch_bounds__(128, 2) void k_gemm(const float* __restrict__ x,
    const float* __restrict__ Wl, const float* __restrict__ Wr,
    float* __restrict__ xl, float* __restrict__ xr){
  __shared__ float xs[GTILE][128];   // 16 KB
  int tid = threadIdx.x;
  int n0 = blockIdx.x * GTILE;
  #pragma unroll
  for (int it=0; it<8; ++it){
    int f = it*512 + tid*4;
    int r = f >> 7, c = f & 127;
    float4 v = make_float4(0.f,0.f,0.f,0.f);
    if (n0 + r < N_NODES) v = *(const float4*)&x[(size_t)(n0+r)*128 + c];
    *(float4*)&xs[r][c] = v;
  }
  __syncthreads();
  int cgrp = tid & 31, ngrp = tid >> 5;
  int c4 = cgrp*4;
  const float* Wlp = Wl + c4;
  const float* Wrp = Wr + c4;
  float accl[8][4], accr[8][4];
  #pragma unroll
  for (int i=0;i<8;++i)
    #pragma unroll
    for (int j=0;j<4;++j){ accl[i][j]=0.f; accr[i][j]=0.f; }

  float4 wlA[4], wrA[4], wlB[4], wrB[4];
  #pragma unroll
  for (int kk=0;kk<4;++kk){
    wlA[kk] = *(const float4*)&Wlp[(size_t)kk*128];
    wrA[kk] = *(const float4*)&Wrp[(size_t)kk*128];
  }
  for (int k=0; k<128; k+=8){
    #pragma unroll
    for (int kk=0;kk<4;++kk){                       // prefetch k+4 into B
      wlB[kk] = *(const float4*)&Wlp[(size_t)(k+4+kk)*128];
      wrB[kk] = *(const float4*)&Wrp[(size_t)(k+4+kk)*128];
    }
    GEMM_CHUNK(k, wlA, wrA)                          // compute k with A
    if (k+8 < 128){
      #pragma unroll
      for (int kk=0;kk<4;++kk){                     // prefetch k+8 into A
        wlA[kk] = *(const float4*)&Wlp[(size_t)(k+8+kk)*128];
        wrA[kk] = *(const float4*)&Wrp[(size_t)(k+8+kk)*128];
      }
    }
    GEMM_CHUNK(k+4, wlB, wrB)                        // compute k+4 with B
  }
  #pragma unroll
  for (int i=0;i<8;++i){
    int node = n0 + ngrp*8 + i;
    if (node < N_NODES){
      float4 vl = make_float4(accl[i][0], accl[i][1], accl[i][2], accl[i][3]);
      float4 vr = make_float4(accr[i][0], accr[i][1], accr[i][2], accr[i][3]);
      *(float4*)&xl[(size_t)node*128 + c4] = vl;
      *(float4*)&xr[(size_t)node*128 + c4] = vr;
    }
  }
}

// ---------------- fused GATv2 attention, one wave per dst node ----------------
// 16-lane head reduction via DPP butterfly (VALU-only, no DS ops).
#define DPP_ADD(x, ctrl) ((x) + __int_as_float(__builtin_amdgcn_update_dpp( \
    0, __float_as_int(x), (ctrl), 0xf, 0xf, true)))
__device__ __forceinline__ float red16(float t){
  t = DPP_ADD(t, 0xB1);
  t = DPP_ADD(t, 0x4E);
  t = DPP_ADD(t, 0x141);
  t = DPP_ADD(t, 0x140);
  return t;
}

__device__ __forceinline__ float lrdot(float2 v, float2 xr2, float2 at2){
  float ex = v.x + xr2.x, ey = v.y + xr2.y;
  ex = ex > 0.f ? ex : NEG_SLOPE*ex;
  ey = ey > 0.f ? ey : NEG_SLOPE*ey;
  return ex*at2.x + ey*at2.y;
}

__global__ __launch_bounds__(256) void k_attn(
    const float* __restrict__ xl, const float* __restrict__ xr,
    const int* __restrict__ row_start, const int* __restrict__ col_src,
    const float* __restrict__ attv, const float* __restrict__ bias,
    const float* __restrict__ Wrel, const float* __restrict__ Wroot,
    const float* __restrict__ brel,
    float* __restrict__ out, float* __restrict__ pbuf, float* __restrict__ score){
  int wid = blockIdx.x*4 + (threadIdx.x >> 6);
  if (wid >= N_NODES) return;
  int lane = threadIdx.x & 63;
  int c2 = lane*2;                       // channels 2l, 2l+1 ; head = lane>>4
  float2 xr2 = *(const float2*)&xr[(size_t)wid*128 + c2];
  float2 at2 = *(const float2*)&attv[c2];
  int row = row_start[wid];
  int deg = row_start[wid+1] - row;
  float d = 0.f, ax = 0.f, ay = 0.f;
  int i = 0;
  for (; i+4 <= deg; i += 4){
    int s0 = col_src[row+i+0];
    int s1 = col_src[row+i+1];
    int s2 = col_src[row+i+2];
    int s3 = col_src[row+i+3];
    float2 v0 = *(const float2*)&xl[(size_t)s0*128 + c2];
    float2 v1 = *(const float2*)&xl[(size_t)s1*128 + c2];
    float2 v2 = *(const float2*)&xl[(size_t)s2*128 + c2];
    float2 v3 = *(const float2*)&xl[(size_t)s3*128 + c2];
    float t0 = red16(lrdot(v0, xr2, at2));
    float t1 = red16(lrdot(v1, xr2, at2));
    float t2 = red16(lrdot(v2, xr2, at2));
    float t3 = red16(lrdot(v3, xr2, at2));
    float w0 = __expf(t0), w1 = __expf(t1), w2 = __expf(t2), w3 = __expf(t3);
    d += (w0 + w1) + (w2 + w3);
    ax = fmaf(w3, v3.x, fmaf(w2, v2.x, fmaf(w1, v1.x, fmaf(w0, v0.x, ax))));
    ay = fmaf(w3, v3.y, fmaf(w2, v2.y, fmaf(w1, v1.y, fmaf(w0, v0.y, ay))));
  }
  for (; i < deg; ++i){
    int s = col_src[row+i];
    float2 v = *(const float2*)&xl[(size_t)s*128 + c2];
    float t = red16(lrdot(v, xr2, at2));
    float w = __expf(t);
    d += w;
    ax = fmaf(w, v.x, ax);
    ay = fmaf(w, v.y, ay);
  }
  float inv = 1.f/d;
  float ox = fmaf(ax, inv, bias[c2]);
  float oy = fmaf(ay, inv, bias[c2+1]);
  *(float2*)&out[(size_t)wid*128 + c2] = make_float2(ox, oy);
  float pv = ox*Wrel[c2]  + oy*Wrel[c2+1];
  float rv = ox*Wroot[c2] + oy*Wroot[c2+1];
  #pragma unroll
  for (int off=1; off<64; off<<=1){
    pv += __shfl_xor(pv, off);
    rv += __shfl_xor(rv, off);
  }
  if (lane == 0){
    pbuf[wid]  = pv;
    score[wid] = brel[0] + rv;
  }
}

// ---------------- SAGPool score: CSR gather (reduction-first; atomics version was +40-70us) ----------------
__global__ __launch_bounds__(256) void k_score(
    const int* __restrict__ row_start, const int* __restrict__ col_src,
    const float* __restrict__ pbuf, float* __restrict__ score){
  int n = blockIdx.x*256 + threadIdx.x;
  if (n >= N_NODES) return;
  int row = row_start[n], deg = row_start[n+1]-row;
  float sc = score[n] - pbuf[n];         // CSR row includes the added self-loop -> remove it
  for (int i=0;i<deg;++i) sc += pbuf[col_src[row+i]];
  score[n] = sc;
}

// ---------------- per-graph softmax + weighted add-pool (batch_index sorted) ----------------
__device__ __forceinline__ int lbound(const int* __restrict__ a, int n, int v){
  int lo=0, hi=n;
  while (lo < hi){ int mid=(lo+hi)>>1; if (a[mid] < v) lo = mid+1; else hi = mid; }
  return lo;
}

__global__ __launch_bounds__(128) void k_pool(
    const int* __restrict__ batch, const float* __restrict__ score,
    const float* __restrict__ out, float* __restrict__ g){
  int b = blockIdx.x;
  int tid = threadIdx.x;
  int start = lbound(batch, N_NODES, b);
  int end   = lbound(batch, N_NODES, b+1);
  __shared__ float red[128];
  __shared__ float sl[128];
  float lm = -FLT_MAX;
  for (int i=start+tid; i<end; i+=128) lm = fmaxf(lm, score[i]);
  red[tid]=lm; __syncthreads();
  for (int off=64; off>0; off>>=1){ if (tid<off) red[tid]=fmaxf(red[tid],red[tid+off]); __syncthreads(); }
  float m = red[0]; __syncthreads();
  float ls = 0.f;
  for (int i=start+tid; i<end; i+=128) ls += __expf(score[i]-m);
  red[tid]=ls; __syncthreads();
  for (int off=64; off>0; off>>=1){ if (tid<off) red[tid]+=red[tid+off]; __syncthreads(); }
  float inv = 1.f / fmaxf(red[0], 1e-16f);
  __syncthreads();
  float acc = 0.f;
  for (int base=start; base<end; base+=128){
    int idx = base+tid;
    sl[tid] = (idx<end) ? __expf(score[idx]-m)*inv : 0.f;
    __syncthreads();
    int lim = min(128, end-base);
    for (int jj=0; jj<lim; ++jj) acc = fmaf(out[(size_t)(base+jj)*128 + tid], sl[jj], acc);
    __syncthreads();
  }
  g[b*128 + tid] = acc;
}

// ---------------- launch ----------------
extern "C" void kernel_launch(void* const* d_in, const int* in_sizes, int n_in,
                              void* d_out, int out_size, void* d_ws, size_t ws_size,
                              hipStream_t stream){
  const float* x    = (const float*)d_in[0];
  const int*   ei   = (const int*)d_in[1];
  const int*   batch= (const int*)d_in[2];
  const float* Wl   = (const float*)d_in[3];
  const float* Wr   = (const float*)d_in[4];
  const float* attv = (const float*)d_in[5];
  const float* bias = (const float*)d_in[6];
  const float* Wrel = (const float*)d_in[7];
  const float* brel = (const float*)d_in[8];
  const float* Wroot= (const float*)d_in[9];
  const int* src0 = ei;
  const int* dst0 = ei + E0;

  float* out = (float*)d_out;                    // [N,128]
  float* g   = out + (size_t)N_NODES*HID;        // [512,128]

  float* xl = (float*)d_ws;
  float* xr = xl + (size_t)N_NODES*HID;
  int* cnt       = (int*)(xr + (size_t)N_NODES*HID);
  int* row_start = cnt + N_NODES;                // N+1
  int* fill      = row_start + N_NODES + 1;
  int* bsum      = fill + N_NODES;
  int* col_src   = bsum + NB_SCAN;               // EP
  float* pbuf    = (float*)(col_src + EP);
  float* score   = pbuf + N_NODES;

  hipMemsetAsync(cnt, 0, N_NODES*sizeof(int), stream);
  k_gemm    <<<dim3((N_NODES+GTILE-1)/GTILE), 128, 0, stream>>>(x, Wl, Wr, xl, xr);
  k_hist    <<<dim3((E0+255)/256),   256, 0, stream>>>(dst0, cnt);
  k_scan1   <<<dim3(NB_SCAN),        256, 0, stream>>>(cnt, bsum);
  k_scan3   <<<dim3(NB_SCAN),        256, 0, stream>>>(cnt, bsum, row_start, fill);
  k_scatter <<<dim3((EP+255)/256),   256, 0, stream>>>(src0, dst0, fill, col_src);
  k_attn    <<<dim3(N_NODES/4),      256, 0, stream>>>(xl, xr, row_start, col_src,
                                                       attv, bias, Wrel, Wroot, brel,
                                                       out, pbuf, score);
  k_score   <<<dim3((N_NODES+255)/256),256, 0, stream>>>(row_start, col_src, pbuf, score);
  k_pool    <<<dim3(NGRAPH),         128, 0, stream>>>(batch, score, out, g);
}